// Round 5
// baseline (7661.574 us; speedup 1.0000x reference)
//
#include <hip/hip_runtime.h>

#define HDIM 2048   // LSTM_DIM
#define G4   8192   // 4*HDIM
#define NB   64     // BATCH
#define NT   512    // MAX_STEPS
#define MEL  512
#define KIN  512    // INPUT_SIZE
#define NWG  256

typedef __attribute__((ext_vector_type(8))) short short8;
typedef __attribute__((ext_vector_type(4))) float f32x4;
typedef __attribute__((ext_vector_type(4))) unsigned uint32x4;

__device__ __forceinline__ unsigned short f2bf(float f){
  union { float f; unsigned u; } v; v.f = f;
  return (unsigned short)((v.u + 0x7fffu + ((v.u >> 16) & 1u)) >> 16);
}
__device__ __forceinline__ float sigm(float x){ return 1.f / (1.f + __expf(-x)); }
__device__ __forceinline__ float tanhfast(float x){ return 1.f - 2.f / (__expf(2.f * x) + 1.f); }

__device__ __forceinline__ f32x4 MF(short8 a, short8 b, f32x4 c){
  return __builtin_amdgcn_mfma_f32_16x16x32_bf16(a, b, c, 0, 0, 0);
}
__device__ __forceinline__ short8 as8(uint32x4 u){
  union { uint32x4 u; short8 s; } x; x.u = u; return x.s;
}
// cached 16B load (L1+L2; freshness via per-step acquire fence)
__device__ __forceinline__ void ldch(uint32x4& d, const unsigned short* p){
  asm volatile("global_load_dwordx4 %0, %1, off"
               : "=&v"(d) : "v"(p) : "memory");
}
// bypass load with wait (barrier slot poll only)
__device__ __forceinline__ uint32x4 ld_bypass4(const unsigned* p){
  uint32x4 r;
  asm volatile("global_load_dwordx4 %0, %1, off sc0 sc1\n\t"
               "s_waitcnt vmcnt(0)"
               : "=v"(r) : "v"(p) : "memory");
  return r;
}

// ---------------- fp32 -> bf16 convert ----------------
__global__ void convert_kernel(const float* __restrict__ src, unsigned short* __restrict__ dst, int n4){
  int stride = gridDim.x * blockDim.x;
  for (int i = blockIdx.x * blockDim.x + threadIdx.x; i < n4; i += stride){
    const float4 v = *(const float4*)(src + (size_t)i * 4);
    uint2 pk;
    pk.x = (unsigned)f2bf(v.x) | ((unsigned)f2bf(v.y) << 16);
    pk.y = (unsigned)f2bf(v.z) | ((unsigned)f2bf(v.w) << 16);
    *(uint2*)(dst + (size_t)i * 4) = pk;
  }
}

// ---------------- b_eff = b_ih + b_hh + W_ih @ b_out ----------------
__global__ void beff_kernel(const float* __restrict__ W_ih, const float* __restrict__ b_ih,
                            const float* __restrict__ b_hh, const float* __restrict__ b_out,
                            float* __restrict__ b_eff){
  int r = blockIdx.x;
  int lane = threadIdx.x;  // 64 threads = 1 wave
  float acc = 0.f;
  for (int k = lane; k < KIN; k += 64) acc += W_ih[(size_t)r * KIN + k] * b_out[k];
  #pragma unroll
  for (int off = 32; off > 0; off >>= 1) acc += __shfl_down(acc, off, 64);
  if (lane == 0) b_eff[r] = b_ih[r] + b_hh[r] + acc;
}

// ---------------- ym1[b][m] = Wout[m]·h0[b] + b_out[m] ----------------
__global__ void ym1_kernel(const float* __restrict__ Wout, const float* __restrict__ h0,
                           const float* __restrict__ b_out, float* __restrict__ ym1){
  const int b = blockIdx.x;
  const int m = blockIdx.y * 64 + threadIdx.x;
  const float* wr = Wout + (size_t)m * HDIM;
  const float* hr = h0 + (size_t)b * HDIM;
  float a0 = 0.f, a1 = 0.f, a2 = 0.f, a3 = 0.f;
  for (int k = 0; k < HDIM; k += 4){
    const float4 wv = *(const float4*)(wr + k);
    const float4 hv = *(const float4*)(hr + k);
    a0 += wv.x * hv.x; a1 += wv.y * hv.y; a2 += wv.z * hv.z; a3 += wv.w * hv.w;
  }
  ym1[(size_t)b * MEL + m] = a0 + a1 + a2 + a3 + b_out[m];
}

// ---------------- corr[r][b] = W_ih[r]·ym1[b] ----------------
__global__ void corr_kernel(const float* __restrict__ Wih, const float* __restrict__ ym1,
                            float* __restrict__ corr){
  const int r = blockIdx.x;
  const int b = threadIdx.x;
  const float* wr = Wih + (size_t)r * KIN;
  const float* yr = ym1 + (size_t)b * MEL;
  float a0 = 0.f, a1 = 0.f, a2 = 0.f, a3 = 0.f;
  for (int m = 0; m < KIN; m += 4){
    const float4 wv = *(const float4*)(wr + m);
    const float4 yv = *(const float4*)(yr + m);
    a0 += wv.x * yv.x; a1 += wv.y * yv.y; a2 += wv.z * yv.z; a3 += wv.w * yv.w;
  }
  corr[(size_t)r * NB + b] = a0 + a1 + a2 + a3;
}

// ---------------- W_eff = bf16( W_hh + W_ih @ W_out )  [8192 x 2048], K=512 ----------------
__global__ __launch_bounds__(256) void weff_gemm(const float* __restrict__ W_ih, const float* __restrict__ W_out,
                                                 const float* __restrict__ W_hh, unsigned short* __restrict__ Weff){
  __shared__ __align__(16) float As[32][68];  // [k][m]
  __shared__ __align__(16) float Bs[32][68];  // [k][n]
  const int bn = blockIdx.x * 64;
  const int bm = blockIdx.y * 64;
  const int t = threadIdx.x;
  const int tx = t & 15, ty = t >> 4;
  float acc[4][4] = {};
  for (int k0 = 0; k0 < KIN; k0 += 32){
    #pragma unroll
    for (int i = 0; i < 2; i++){
      int f = t + i * 256;
      int row = f >> 3, c4 = (f & 7) * 4;
      const float4 v = *(const float4*)(W_ih + (size_t)(bm + row) * KIN + k0 + c4);
      As[c4 + 0][row] = v.x; As[c4 + 1][row] = v.y; As[c4 + 2][row] = v.z; As[c4 + 3][row] = v.w;
    }
    #pragma unroll
    for (int i = 0; i < 2; i++){
      int f = t + i * 256;
      int kr = f >> 4, c4 = (f & 15) * 4;
      *(float4*)&Bs[kr][c4] = *(const float4*)(W_out + (size_t)(k0 + kr) * HDIM + bn + c4);
    }
    __syncthreads();
    #pragma unroll
    for (int kk = 0; kk < 32; kk++){
      const float4 av = *(const float4*)&As[kk][ty * 4];
      const float4 bv = *(const float4*)&Bs[kk][tx * 4];
      const float ar[4] = {av.x, av.y, av.z, av.w};
      const float br[4] = {bv.x, bv.y, bv.z, bv.w};
      #pragma unroll
      for (int i = 0; i < 4; i++)
        #pragma unroll
        for (int j = 0; j < 4; j++)
          acc[i][j] += ar[i] * br[j];
    }
    __syncthreads();
  }
  #pragma unroll
  for (int i = 0; i < 4; i++){
    const size_t row = (size_t)bm + ty * 4 + i;
    const float4 wh = *(const float4*)(W_hh + row * HDIM + bn + tx * 4);
    uint2 pk;
    pk.x = (unsigned)f2bf(acc[i][0] + wh.x) | ((unsigned)f2bf(acc[i][1] + wh.y) << 16);
    pk.y = (unsigned)f2bf(acc[i][2] + wh.z) | ((unsigned)f2bf(acc[i][3] + wh.w) << 16);
    *(uint2*)(Weff + row * HDIM + bn + tx * 4) = pk;
  }
}

// ---------------- lightweight global barrier + acquire (L2 inv) ----------------
// Arrival: leader bypass-stores step count to its slot. Wait: wave 0 polls all 256
// slots via bypass dwordx4. Release: h stores are agent-scope (write-through to IC).
// Acquire: leader buffer_inv (L1+L2 tag invalidate) so cached h loads see fresh IC data.
__device__ __forceinline__ void gbar(unsigned* __restrict__ slots, int w, int tid, unsigned tgt){
  __syncthreads();   // all waves' h stores drained (vmcnt 0) before arrival
  if (tid == 0)
    __hip_atomic_store(slots + w, tgt, __ATOMIC_RELAXED, __HIP_MEMORY_SCOPE_AGENT);
  if (tid < 64){
    const unsigned* sp = slots + tid * 4;
    while (true){
      uint32x4 vv = ld_bypass4(sp);
      unsigned m0 = vv.x < vv.y ? vv.x : vv.y;
      unsigned m1 = vv.z < vv.w ? vv.z : vv.w;
      unsigned m = m0 < m1 ? m0 : m1;
      if (__all((int)(m >= tgt))) break;
      __builtin_amdgcn_s_sleep(1);
    }
  }
  __syncthreads();   // all 256 WGs arrived
  if (tid == 0) __builtin_amdgcn_fence(__ATOMIC_ACQUIRE, "agent");  // inv L1/L2
  __syncthreads();   // inv complete before any h load of next step
}

// ---------------- persistent decoder: weights in VGPRs, h via L2 ----------------
// 256 WGs x 512 thr (8 waves). WG w owns h-cols [8w,8w+8) -> 32 gate rows + 2 W_out rows.
// Wave v holds A-fragments for k-slice [256v,256v+256) in VGPRs.
// Per step: 8 k32-iters x 4 batch-tiles; B (h) via cached loads, TRIPLE-buffered regs
// (vmcnt(8): 3 groups in flight covers L2/IC latency).
// Gate partials summed via LDS exchange exf[8v][32row][64b] (phys_b = b ^ ((row&7)<<2)).
#define EXYOFF 16384               // f32 index of y-exchange
#define LDSX   (16384*4 + 8*2*64*4)  // 64KB gates + 4KB y = 69632

__global__ void __launch_bounds__(512, 2) decoder_coop(
    const unsigned short* __restrict__ Weff_b,
    const unsigned short* __restrict__ Wout_b,
    const float* __restrict__ b_eff,
    const float* __restrict__ corr,
    const float* __restrict__ c0,
    const float* __restrict__ b_out,
    unsigned short* __restrict__ hbuf,   // [2][64][2048] bf16; hbuf[0] = bf16(h0)
    unsigned* __restrict__ slots,        // [256] zeroed
    float* __restrict__ out)             // [64][512][512]
{
  extern __shared__ char smem[];
  float* exf = (float*)smem;
  float* eyf = exf + EXYOFF;
  const int w    = blockIdx.x;
  const int tid  = threadIdx.x;
  const int v    = tid >> 6;           // wave = k-slice owner
  const int lane = tid & 63;
  const int col  = lane & 15;
  const int q    = lane >> 4;
  const int kbase = v * 256;

  // ---- A-fragment preload into VGPRs ----
  short8 A0[8], A1[8], Ay[8];
  #pragma unroll
  for (int it = 0; it < 8; ++it){
    {
      const int row = col;
      const int grow = (row >> 3) * HDIM + w * 8 + (row & 7);
      A0[it] = *(const short8*)(Weff_b + (size_t)grow * HDIM + kbase + it * 32 + q * 8);
    }
    {
      const int row = 16 + col;
      const int grow = (row >> 3) * HDIM + w * 8 + (row & 7);
      A1[it] = *(const short8*)(Weff_b + (size_t)grow * HDIM + kbase + it * 32 + q * 8);
    }
    if (col < 2)
      Ay[it] = *(const short8*)(Wout_b + (size_t)(w * 2 + col) * HDIM + kbase + it * 32 + q * 8);
    else { short8 z = {0,0,0,0,0,0,0,0}; Ay[it] = z; }
  }

  // ---- reduction-thread constants (tid<256: thread = (j, batch-pair b2)) ----
  const int j  = tid & 7;
  const int b2 = (tid >> 3) & 31;
  const int rj = w * 8 + j;
  float be[4], cE[4], cO[4];
  float cs_e = 0.f, cs_o = 0.f;
  if (tid < 256){
    #pragma unroll
    for (int g = 0; g < 4; ++g){
      be[g] = b_eff[g * HDIM + rj];
      const float2 cc = *(const float2*)(corr + ((size_t)(g * HDIM + rj)) * NB + 2 * b2);
      cE[g] = cc.x; cO[g] = cc.y;
    }
    cs_e = c0[(size_t)(2 * b2) * HDIM + rj];
    cs_o = c0[(size_t)(2 * b2 + 1) * HDIM + rj];
  }
  float byo = 0.f; int yp = 0, yb = 0;
  if (tid >= 256 && tid < 384){
    const int yt = tid - 256; yp = yt & 1; yb = yt >> 1; byo = b_out[w * 2 + yp];
  }

  // per-lane B element-offset bases (const over t)
  int boff[4];
  #pragma unroll
  for (int bt = 0; bt < 4; ++bt) boff[bt] = (bt * 16 + col) * HDIM + kbase + q * 8;

#define LDG(GBUF, OFF) { \
    ldch(GBUF[0], hcur + boff[0] + (OFF) * 32); \
    ldch(GBUF[1], hcur + boff[1] + (OFF) * 32); \
    ldch(GBUF[2], hcur + boff[2] + (OFF) * 32); \
    ldch(GBUF[3], hcur + boff[3] + (OFF) * 32); }
#define WAITV(N) asm volatile("s_waitcnt vmcnt(" #N ")" ::: "memory"); __builtin_amdgcn_sched_barrier(0);
#define MFM(IT, GBUF) { \
    _Pragma("unroll") \
    for (int bt = 0; bt < 4; ++bt){ \
      const short8 bv = as8(GBUF[bt]); \
      acc0[bt] = MF(A0[IT], bv, acc0[bt]); \
      acc1[bt] = MF(A1[IT], bv, acc1[bt]); \
      accy[bt] = MF(Ay[IT], bv, accy[bt]); } }

  for (int t = 0; t < NT; ++t){
    const unsigned short* hcur = hbuf + (size_t)(t & 1) * NB * HDIM;
    uint32x4 G0[4], G1[4], G2[4];
    f32x4 acc0[4], acc1[4], accy[4];
    #pragma unroll
    for (int bt = 0; bt < 4; ++bt){ f32x4 z = {0.f,0.f,0.f,0.f}; acc0[bt]=z; acc1[bt]=z; accy[bt]=z; }

    LDG(G0, 0) LDG(G1, 1)
    LDG(G2, 2) WAITV(8) MFM(0, G0)
    LDG(G0, 3) WAITV(8) MFM(1, G1)
    LDG(G1, 4) WAITV(8) MFM(2, G2)
    LDG(G2, 5) WAITV(8) MFM(3, G0)
    LDG(G0, 6) WAITV(8) MFM(4, G1)
    LDG(G1, 7) WAITV(8) MFM(5, G2)
    WAITV(4) MFM(6, G0)
    WAITV(0) MFM(7, G1)

    // ---- exchange stores (swizzled: phys_b = b ^ ((row&7)<<2), <=2-way) ----
    #pragma unroll
    for (int bt = 0; bt < 4; ++bt){
      const int b = bt * 16 + col;
      #pragma unroll
      for (int e = 0; e < 4; ++e){
        const int r0 = q * 4 + e;
        exf[(v * 32 + r0) * 64 + (b ^ ((r0 & 7) << 2))] = acc0[bt][e];
        const int r1 = 16 + q * 4 + e;
        exf[(v * 32 + r1) * 64 + (b ^ ((r1 & 7) << 2))] = acc1[bt][e];
      }
      if (q == 0){
        eyf[(v * 2 + 0) * 64 + b] = accy[bt][0];
        eyf[(v * 2 + 1) * 64 + b] = accy[bt][1];
      }
    }
    __syncthreads();

    if (tid < 256){
      // ---- 8-way k-partial reduction + LSTM cell for (j, 2*b2) and (j, 2*b2+1) ----
      float ge[4] = {0,0,0,0}, go[4] = {0,0,0,0};
      #pragma unroll
      for (int g = 0; g < 4; ++g){
        #pragma unroll
        for (int vv = 0; vv < 8; ++vv){
          const float2 pr = *(const float2*)&exf[(vv * 32 + g * 8 + j) * 64 + ((2 * b2) ^ (j << 2))];
          ge[g] += pr.x; go[g] += pr.y;
        }
      }
      float ie = ge[0] + be[0], fe = ge[1] + be[1], gge = ge[2] + be[2], oe = ge[3] + be[3];
      float io = go[0] + be[0], fo = go[1] + be[1], ggo = go[2] + be[2], oo = go[3] + be[3];
      if (t == 0){
        ie -= cE[0]; fe -= cE[1]; gge -= cE[2]; oe -= cE[3];
        io -= cO[0]; fo -= cO[1]; ggo -= cO[2]; oo -= cO[3];
      }
      const float gi0 = sigm(ie), gf0 = sigm(fe), gg0 = tanhfast(gge), go0 = sigm(oe);
      cs_e = gf0 * cs_e + gi0 * gg0;
      const float hn_e = go0 * tanhfast(cs_e);
      const float gi1 = sigm(io), gf1 = sigm(fo), gg1 = tanhfast(ggo), go1 = sigm(oo);
      cs_o = gf1 * cs_o + gi1 * gg1;
      const float hn_o = go1 * tanhfast(cs_o);

      // pack 2 adjacent j via shfl, store 4B to IC (agent scope)
      const float pe = __shfl_xor(hn_e, 1, 64);
      const float po = __shfl_xor(hn_o, 1, 64);
      unsigned short* hdst = hbuf + (size_t)((t + 1) & 1) * NB * HDIM;
      if ((j & 1) == 0){
        const unsigned pk = (unsigned)f2bf(hn_e) | ((unsigned)f2bf(pe) << 16);
        __hip_atomic_store((unsigned*)(hdst + (size_t)(2 * b2) * HDIM + rj), pk,
                           __ATOMIC_RELAXED, __HIP_MEMORY_SCOPE_AGENT);
      } else {
        const unsigned pk = (unsigned)f2bf(po) | ((unsigned)f2bf(hn_o) << 16);
        __hip_atomic_store((unsigned*)(hdst + (size_t)(2 * b2 + 1) * HDIM + rj - 1), pk,
                           __ATOMIC_RELAXED, __HIP_MEMORY_SCOPE_AGENT);
      }
    } else if (tid < 384 && t >= 1){
      // ---- y reduction: out[b][t-1][2w+yp] ----
      float yv = byo;
      #pragma unroll
      for (int vv = 0; vv < 8; ++vv) yv += eyf[(vv * 2 + yp) * 64 + yb];
      out[((size_t)yb * NT + (t - 1)) * MEL + w * 2 + yp] = yv;
    }
    gbar(slots, w, tid, (unsigned)(t + 1));
  }

  // ---- final frame: y_511 from h_512 (in hbuf[0], NT even) ----
  {
    const unsigned short* hcur = hbuf;   // (NT&1)==0
    f32x4 accy[4];
    #pragma unroll
    for (int bt = 0; bt < 4; ++bt){ f32x4 z = {0.f,0.f,0.f,0.f}; accy[bt] = z; }
    #pragma unroll
    for (int it = 0; it < 8; ++it){
      uint32x4 g[4];
      #pragma unroll
      for (int bt = 0; bt < 4; ++bt) ldch(g[bt], hcur + boff[bt] + it * 32);
      asm volatile("s_waitcnt vmcnt(0)" ::: "memory");
      __builtin_amdgcn_sched_barrier(0);
      #pragma unroll
      for (int bt = 0; bt < 4; ++bt) accy[bt] = MF(Ay[it], as8(g[bt]), accy[bt]);
    }
    #pragma unroll
    for (int bt = 0; bt < 4; ++bt){
      const int b = bt * 16 + col;
      if (q == 0){
        eyf[(v * 2 + 0) * 64 + b] = accy[bt][0];
        eyf[(v * 2 + 1) * 64 + b] = accy[bt][1];
      }
    }
    __syncthreads();
    if (tid >= 256 && tid < 384){
      float yv = byo;
      #pragma unroll
      for (int vv = 0; vv < 8; ++vv) yv += eyf[(vv * 2 + yp) * 64 + yb];
      out[((size_t)yb * NT + 511) * MEL + w * 2 + yp] = yv;
    }
  }
}

extern "C" void kernel_launch(void* const* d_in, const int* in_sizes, int n_in,
                              void* d_out, int out_size, void* d_ws, size_t ws_size,
                              hipStream_t stream){
  (void)in_sizes; (void)n_in; (void)out_size; (void)ws_size;
  const float* h0    = (const float*)d_in[1];
  const float* c0    = (const float*)d_in[2];
  const float* W_ih  = (const float*)d_in[3];
  const float* W_hh  = (const float*)d_in[4];
  const float* b_ih  = (const float*)d_in[5];
  const float* b_hh  = (const float*)d_in[6];
  const float* W_out = (const float*)d_in[7];
  const float* b_out = (const float*)d_in[8];
  float* out = (float*)d_out;

  char* p = (char*)d_ws;
  unsigned short* weff_b = (unsigned short*)p; p += (size_t)G4 * HDIM * 2;   // 33.5 MB
  unsigned short* wout_b = (unsigned short*)p; p += (size_t)MEL * HDIM * 2;  // 2 MB
  float* beff = (float*)p;  p += (size_t)G4 * 4;
  float* corr = (float*)p;  p += (size_t)G4 * NB * 4;                        // 2 MB
  float* ym1  = (float*)p;  p += (size_t)NB * MEL * 4;                       // 128 KB
  unsigned short* hbuf = (unsigned short*)p; p += (size_t)2 * NB * HDIM * 2; // 512 KB
  unsigned* slots = (unsigned*)p; p += NWG * sizeof(unsigned);

  hipMemsetAsync(slots, 0, NWG * sizeof(unsigned), stream);
  convert_kernel<<<256, 256, 0, stream>>>(W_out, wout_b, MEL * HDIM / 4);
  convert_kernel<<<64, 256, 0, stream>>>(h0, hbuf, NB * HDIM / 4);
  beff_kernel<<<G4, 64, 0, stream>>>(W_ih, b_ih, b_hh, b_out, beff);
  ym1_kernel<<<dim3(NB, MEL / 64), 64, 0, stream>>>(W_out, h0, b_out, ym1);
  corr_kernel<<<G4, NB, 0, stream>>>(W_ih, ym1, corr);
  weff_gemm<<<dim3(HDIM / 64, G4 / 64), 256, 0, stream>>>(W_ih, W_out, W_hh, weff_b);

  hipFuncSetAttribute((const void*)decoder_coop, hipFuncAttributeMaxDynamicSharedMemorySize, LDSX);
  void* kargs[] = { (void*)&weff_b, (void*)&wout_b, (void*)&beff, (void*)&corr,
                    (void*)&c0, (void*)&b_out, (void*)&hbuf, (void*)&slots, (void*)&out };
  hipLaunchCooperativeKernel((const void*)decoder_coop, dim3(NWG), dim3(512), kargs, LDSX, stream);
}

// Round 6
// 5617.455 us; speedup vs baseline: 1.3639x; 1.3639x over previous
//
#include <hip/hip_runtime.h>

#define HDIM 2048   // LSTM_DIM
#define G4   8192   // 4*HDIM
#define NB   64     // BATCH
#define NT   512    // MAX_STEPS
#define MEL  512
#define KIN  512    // INPUT_SIZE
#define NWG  256

typedef __attribute__((ext_vector_type(8))) short short8;
typedef __attribute__((ext_vector_type(4))) float f32x4;
typedef __attribute__((ext_vector_type(4))) unsigned uint32x4;

__device__ __forceinline__ unsigned short f2bf(float f){
  union { float f; unsigned u; } v; v.f = f;
  return (unsigned short)((v.u + 0x7fffu + ((v.u >> 16) & 1u)) >> 16);
}
__device__ __forceinline__ float sigm(float x){ return 1.f / (1.f + __expf(-x)); }
__device__ __forceinline__ float tanhfast(float x){ return 1.f - 2.f / (__expf(2.f * x) + 1.f); }

__device__ __forceinline__ f32x4 MF(short8 a, short8 b, f32x4 c){
  return __builtin_amdgcn_mfma_f32_16x16x32_bf16(a, b, c, 0, 0, 0);
}
__device__ __forceinline__ short8 as8(uint32x4 u){
  union { uint32x4 u; short8 s; } x; x.u = u; return x.s;
}
// IC bypass 16B load (no waitcnt inside; caller waits via counted vmcnt)
__device__ __forceinline__ void ld4b(uint32x4& d, const unsigned short* p){
  asm volatile("global_load_dwordx4 %0, %1, off sc0 sc1"
               : "=&v"(d) : "v"(p) : "memory");
}
// bypass load with wait (slot poll)
__device__ __forceinline__ uint32x4 ld_bypass4(const unsigned* p){
  uint32x4 r;
  asm volatile("global_load_dwordx4 %0, %1, off sc0 sc1\n\t"
               "s_waitcnt vmcnt(0)"
               : "=v"(r) : "v"(p) : "memory");
  return r;
}

// ---------------- fp32 -> bf16 convert ----------------
__global__ void convert_kernel(const float* __restrict__ src, unsigned short* __restrict__ dst, int n4){
  int stride = gridDim.x * blockDim.x;
  for (int i = blockIdx.x * blockDim.x + threadIdx.x; i < n4; i += stride){
    const float4 v = *(const float4*)(src + (size_t)i * 4);
    uint2 pk;
    pk.x = (unsigned)f2bf(v.x) | ((unsigned)f2bf(v.y) << 16);
    pk.y = (unsigned)f2bf(v.z) | ((unsigned)f2bf(v.w) << 16);
    *(uint2*)(dst + (size_t)i * 4) = pk;
  }
}

// ---------------- b_eff = b_ih + b_hh + W_ih @ b_out ----------------
__global__ void beff_kernel(const float* __restrict__ W_ih, const float* __restrict__ b_ih,
                            const float* __restrict__ b_hh, const float* __restrict__ b_out,
                            float* __restrict__ b_eff){
  int r = blockIdx.x;
  int lane = threadIdx.x;  // 64 threads = 1 wave
  float acc = 0.f;
  for (int k = lane; k < KIN; k += 64) acc += W_ih[(size_t)r * KIN + k] * b_out[k];
  #pragma unroll
  for (int off = 32; off > 0; off >>= 1) acc += __shfl_down(acc, off, 64);
  if (lane == 0) b_eff[r] = b_ih[r] + b_hh[r] + acc;
}

// ---------------- ym1[b][m] = Wout[m]·h0[b] + b_out[m] ----------------
__global__ void ym1_kernel(const float* __restrict__ Wout, const float* __restrict__ h0,
                           const float* __restrict__ b_out, float* __restrict__ ym1){
  const int b = blockIdx.x;
  const int m = blockIdx.y * 64 + threadIdx.x;
  const float* wr = Wout + (size_t)m * HDIM;
  const float* hr = h0 + (size_t)b * HDIM;
  float a0 = 0.f, a1 = 0.f, a2 = 0.f, a3 = 0.f;
  for (int k = 0; k < HDIM; k += 4){
    const float4 wv = *(const float4*)(wr + k);
    const float4 hv = *(const float4*)(hr + k);
    a0 += wv.x * hv.x; a1 += wv.y * hv.y; a2 += wv.z * hv.z; a3 += wv.w * hv.w;
  }
  ym1[(size_t)b * MEL + m] = a0 + a1 + a2 + a3 + b_out[m];
}

// ---------------- corr[r][b] = W_ih[r]·ym1[b] ----------------
__global__ void corr_kernel(const float* __restrict__ Wih, const float* __restrict__ ym1,
                            float* __restrict__ corr){
  const int r = blockIdx.x;
  const int b = threadIdx.x;
  const float* wr = Wih + (size_t)r * KIN;
  const float* yr = ym1 + (size_t)b * MEL;
  float a0 = 0.f, a1 = 0.f, a2 = 0.f, a3 = 0.f;
  for (int m = 0; m < KIN; m += 4){
    const float4 wv = *(const float4*)(wr + m);
    const float4 yv = *(const float4*)(yr + m);
    a0 += wv.x * yv.x; a1 += wv.y * yv.y; a2 += wv.z * yv.z; a3 += wv.w * yv.w;
  }
  corr[(size_t)r * NB + b] = a0 + a1 + a2 + a3;
}

// ---------------- W_eff = bf16( W_hh + W_ih @ W_out )  [8192 x 2048], K=512 ----------------
__global__ __launch_bounds__(256) void weff_gemm(const float* __restrict__ W_ih, const float* __restrict__ W_out,
                                                 const float* __restrict__ W_hh, unsigned short* __restrict__ Weff){
  __shared__ __align__(16) float As[32][68];  // [k][m]
  __shared__ __align__(16) float Bs[32][68];  // [k][n]
  const int bn = blockIdx.x * 64;
  const int bm = blockIdx.y * 64;
  const int t = threadIdx.x;
  const int tx = t & 15, ty = t >> 4;
  float acc[4][4] = {};
  for (int k0 = 0; k0 < KIN; k0 += 32){
    #pragma unroll
    for (int i = 0; i < 2; i++){
      int f = t + i * 256;
      int row = f >> 3, c4 = (f & 7) * 4;
      const float4 v = *(const float4*)(W_ih + (size_t)(bm + row) * KIN + k0 + c4);
      As[c4 + 0][row] = v.x; As[c4 + 1][row] = v.y; As[c4 + 2][row] = v.z; As[c4 + 3][row] = v.w;
    }
    #pragma unroll
    for (int i = 0; i < 2; i++){
      int f = t + i * 256;
      int kr = f >> 4, c4 = (f & 15) * 4;
      *(float4*)&Bs[kr][c4] = *(const float4*)(W_out + (size_t)(k0 + kr) * HDIM + bn + c4);
    }
    __syncthreads();
    #pragma unroll
    for (int kk = 0; kk < 32; kk++){
      const float4 av = *(const float4*)&As[kk][ty * 4];
      const float4 bv = *(const float4*)&Bs[kk][tx * 4];
      const float ar[4] = {av.x, av.y, av.z, av.w};
      const float br[4] = {bv.x, bv.y, bv.z, bv.w};
      #pragma unroll
      for (int i = 0; i < 4; i++)
        #pragma unroll
        for (int j = 0; j < 4; j++)
          acc[i][j] += ar[i] * br[j];
    }
    __syncthreads();
  }
  #pragma unroll
  for (int i = 0; i < 4; i++){
    const size_t row = (size_t)bm + ty * 4 + i;
    const float4 wh = *(const float4*)(W_hh + row * HDIM + bn + tx * 4);
    uint2 pk;
    pk.x = (unsigned)f2bf(acc[i][0] + wh.x) | ((unsigned)f2bf(acc[i][1] + wh.y) << 16);
    pk.y = (unsigned)f2bf(acc[i][2] + wh.z) | ((unsigned)f2bf(acc[i][3] + wh.w) << 16);
    *(uint2*)(Weff + row * HDIM + bn + tx * 4) = pk;
  }
}

// ---------------- per-wave wait: all 256 slots >= tgt (IC-coherent, no fence) ----------------
__device__ __forceinline__ void wait_slots(const unsigned* __restrict__ slots, int lane, unsigned tgt){
  const unsigned* sp = slots + lane * 4;
  while (true){
    uint32x4 vv = ld_bypass4(sp);
    unsigned m0 = vv.x < vv.y ? vv.x : vv.y;
    unsigned m1 = vv.z < vv.w ? vv.z : vv.w;
    unsigned m = m0 < m1 ? m0 : m1;
    if (__all((int)(m >= tgt))) break;
    __builtin_amdgcn_s_sleep(1);
  }
}

// ---------------- persistent decoder: two-stream batch interleave ----------------
// 256 WGs x 512 thr (8 waves). WG w owns h-cols [8w,8w+8) -> 32 gate rows + 2 W_out rows.
// Wave v holds A-fragments for k-slice [256v,256v+256) in VGPRs.
// Streams: s=0 -> batches 0-31, s=1 -> batches 32-63; independent slot chains.
// Per WG: ... wait0(t) C0(t) wait1(t) C1(t) wait0(t+1) ... -> barrier latency of one
// stream hides under the other stream's compute. h via IC-bypass loads (R4 path).
__global__ void __launch_bounds__(512, 1) decoder_coop(
    const unsigned short* __restrict__ Weff_b,
    const unsigned short* __restrict__ Wout_b,
    const float* __restrict__ b_eff,
    const float* __restrict__ corr,
    const float* __restrict__ c0,
    const float* __restrict__ b_out,
    unsigned short* __restrict__ hbuf,   // [2][64][2048] bf16; hbuf[0] = bf16(h0)
    unsigned* __restrict__ slots0,       // [256] zeroed
    unsigned* __restrict__ slots1,       // [256] zeroed
    float* __restrict__ out)             // [64][512][512]
{
  __shared__ float exf[8192];            // [8v][32row][32b] gate exchange (swizzled)
  __shared__ float eyf[512];             // [8v][2][32b] y exchange
  const int w    = blockIdx.x;
  const int tid  = threadIdx.x;
  const int v    = tid >> 6;
  const int lane = tid & 63;
  const int col  = lane & 15;
  const int q    = lane >> 4;
  const int kbase = v * 256;

  // ---- A-fragment preload into VGPRs ----
  short8 A0[8], A1[8], Ay[8];
  #pragma unroll
  for (int it = 0; it < 8; ++it){
    {
      const int row = col;
      const int grow = (row >> 3) * HDIM + w * 8 + (row & 7);
      A0[it] = *(const short8*)(Weff_b + (size_t)grow * HDIM + kbase + it * 32 + q * 8);
    }
    {
      const int row = 16 + col;
      const int grow = (row >> 3) * HDIM + w * 8 + (row & 7);
      A1[it] = *(const short8*)(Weff_b + (size_t)grow * HDIM + kbase + it * 32 + q * 8);
    }
    if (col < 2)
      Ay[it] = *(const short8*)(Wout_b + (size_t)(w * 2 + col) * HDIM + kbase + it * 32 + q * 8);
    else { short8 z = {0,0,0,0,0,0,0,0}; Ay[it] = z; }
  }

  // ---- reduce-thread constants: tid<256 -> (j, global batch-pair p); stream sp=p>>4 ----
  const int j  = tid & 7;
  const int p  = (tid >> 3) & 31;
  const int sp = p >> 4;
  const int rj = w * 8 + j;
  float be[4], cE[4], cO[4];
  float cs_e = 0.f, cs_o = 0.f;
  if (tid < 256){
    #pragma unroll
    for (int g = 0; g < 4; ++g){
      be[g] = b_eff[g * HDIM + rj];
      const float2 cc = *(const float2*)(corr + ((size_t)(g * HDIM + rj)) * NB + 2 * p);
      cE[g] = cc.x; cO[g] = cc.y;
    }
    cs_e = c0[(size_t)(2 * p) * HDIM + rj];
    cs_o = c0[(size_t)(2 * p + 1) * HDIM + rj];
  }
  const bool isY = (tid >= 256 && tid < 384);
  float byo = 0.f; int yp = 0, yb = 0;
  if (isY){ const int yt = tid - 256; yp = yt & 1; yb = yt >> 1; byo = b_out[w * 2 + yp]; }
  const int ys = yb >> 5;               // y-thread's stream

  // per-lane B offsets: boff[s][bt]
  int boff[2][2];
  #pragma unroll
  for (int s = 0; s < 2; ++s)
    #pragma unroll
    for (int bt = 0; bt < 2; ++bt)
      boff[s][bt] = (s * 32 + bt * 16 + col) * HDIM + kbase + q * 8;

#define LD2(G, OFF) { ld4b(G[0], hcur + bo0 + (OFF) * 32); ld4b(G[1], hcur + bo1 + (OFF) * 32); }
#define WAITV(N) asm volatile("s_waitcnt vmcnt(" #N ")" ::: "memory"); __builtin_amdgcn_sched_barrier(0);
#define MFM2(IT, G) { \
    const short8 bv0 = as8(G[0]); const short8 bv1 = as8(G[1]); \
    acc0[0] = MF(A0[IT], bv0, acc0[0]); acc1[0] = MF(A1[IT], bv0, acc1[0]); accy[0] = MF(Ay[IT], bv0, accy[0]); \
    acc0[1] = MF(A0[IT], bv1, acc0[1]); acc1[1] = MF(A1[IT], bv1, acc1[1]); accy[1] = MF(Ay[IT], bv1, accy[1]); }

  for (int t = 0; t < NT; ++t){
    #pragma unroll
    for (int s = 0; s < 2; ++s){
      unsigned* slots = s ? slots1 : slots0;
      if (t) wait_slots(slots, lane, (unsigned)t);   // per-wave; usually already satisfied

      const unsigned short* hcur = hbuf + (size_t)(t & 1) * NB * HDIM;
      const int bo0 = boff[s][0], bo1 = boff[s][1];
      uint32x4 G0[2], G1[2], G2[2];
      f32x4 acc0[2], acc1[2], accy[2];
      #pragma unroll
      for (int bt = 0; bt < 2; ++bt){ f32x4 z = {0.f,0.f,0.f,0.f}; acc0[bt]=z; acc1[bt]=z; accy[bt]=z; }

      LD2(G0, 0) LD2(G1, 1) LD2(G2, 2)
      WAITV(4) MFM2(0, G0) LD2(G0, 3)
      WAITV(4) MFM2(1, G1) LD2(G1, 4)
      WAITV(4) MFM2(2, G2) LD2(G2, 5)
      WAITV(4) MFM2(3, G0) LD2(G0, 6)
      WAITV(4) MFM2(4, G1) LD2(G1, 7)
      WAITV(4) MFM2(5, G2)
      WAITV(2) MFM2(6, G0)
      WAITV(0) MFM2(7, G1)

      // ---- exchange stores (bs in [0,32), swizzle bs ^ ((row&7)<<2)) ----
      #pragma unroll
      for (int bt = 0; bt < 2; ++bt){
        const int bs = bt * 16 + col;
        #pragma unroll
        for (int e = 0; e < 4; ++e){
          const int r0 = q * 4 + e;
          exf[(v * 32 + r0) * 32 + (bs ^ ((r0 & 7) << 2))] = acc0[bt][e];
          const int r1 = 16 + q * 4 + e;
          exf[(v * 32 + r1) * 32 + (bs ^ ((r1 & 7) << 2))] = acc1[bt][e];
        }
        if (q == 0){
          eyf[(v * 2 + 0) * 32 + bs] = accy[bt][0];
          eyf[(v * 2 + 1) * 32 + bs] = accy[bt][1];
        }
      }
      __syncthreads();

      if (tid < 256 && sp == s){
        const int bse = 2 * (p & 15);     // even batch-in-stream index
        float ge[4] = {0,0,0,0}, go[4] = {0,0,0,0};
        #pragma unroll
        for (int g = 0; g < 4; ++g){
          #pragma unroll
          for (int vv = 0; vv < 8; ++vv){
            const float2 pr = *(const float2*)&exf[(vv * 32 + g * 8 + j) * 32 + (bse ^ (j << 2))];
            ge[g] += pr.x; go[g] += pr.y;
          }
        }
        float ie = ge[0] + be[0], fe = ge[1] + be[1], gge = ge[2] + be[2], oe = ge[3] + be[3];
        float io = go[0] + be[0], fo = go[1] + be[1], ggo = go[2] + be[2], oo = go[3] + be[3];
        if (t == 0){
          ie -= cE[0]; fe -= cE[1]; gge -= cE[2]; oe -= cE[3];
          io -= cO[0]; fo -= cO[1]; ggo -= cO[2]; oo -= cO[3];
        }
        const float gi0 = sigm(ie), gf0 = sigm(fe), gg0 = tanhfast(gge), go0 = sigm(oe);
        cs_e = gf0 * cs_e + gi0 * gg0;
        const float hn_e = go0 * tanhfast(cs_e);
        const float gi1 = sigm(io), gf1 = sigm(fo), gg1 = tanhfast(ggo), go1 = sigm(oo);
        cs_o = gf1 * cs_o + gi1 * gg1;
        const float hn_o = go1 * tanhfast(cs_o);

        const float pe = __shfl_xor(hn_e, 1, 64);
        const float po = __shfl_xor(hn_o, 1, 64);
        unsigned short* hdst = hbuf + (size_t)((t + 1) & 1) * NB * HDIM;
        if ((j & 1) == 0){
          const unsigned pk = (unsigned)f2bf(hn_e) | ((unsigned)f2bf(pe) << 16);
          __hip_atomic_store((unsigned*)(hdst + (size_t)(2 * p) * HDIM + rj), pk,
                             __ATOMIC_RELAXED, __HIP_MEMORY_SCOPE_AGENT);
        } else {
          const unsigned pk = (unsigned)f2bf(po) | ((unsigned)f2bf(hn_o) << 16);
          __hip_atomic_store((unsigned*)(hdst + (size_t)(2 * p + 1) * HDIM + rj - 1), pk,
                             __ATOMIC_RELAXED, __HIP_MEMORY_SCOPE_AGENT);
        }
      } else if (isY && ys == s && t >= 1){
        float yv = byo;
        #pragma unroll
        for (int vv = 0; vv < 8; ++vv) yv += eyf[(vv * 2 + yp) * 32 + (yb & 31)];
        out[((size_t)yb * NT + (t - 1)) * MEL + w * 2 + yp] = yv;
      }
      __syncthreads();   // drains vmcnt (h stores visible at IC) + protects exf reuse
      if (tid == 0)
        __hip_atomic_store(slots + w, (unsigned)(t + 1), __ATOMIC_RELAXED, __HIP_MEMORY_SCOPE_AGENT);
    }
  }

  // ---- final frame per stream: y_511 = h_512 @ Wout^T + b_out (h_512 in hbuf[0]) ----
  #pragma unroll
  for (int s = 0; s < 2; ++s){
    wait_slots(s ? slots1 : slots0, lane, (unsigned)NT);
    const unsigned short* hcur = hbuf;   // NT even
    const int bo0 = boff[s][0], bo1 = boff[s][1];
    f32x4 ay0 = {0.f,0.f,0.f,0.f}, ay1 = {0.f,0.f,0.f,0.f};
    #pragma unroll
    for (int it = 0; it < 8; ++it){
      uint32x4 g0, g1;
      ld4b(g0, hcur + bo0 + it * 32);
      ld4b(g1, hcur + bo1 + it * 32);
      asm volatile("s_waitcnt vmcnt(0)" ::: "memory");
      __builtin_amdgcn_sched_barrier(0);
      ay0 = MF(Ay[it], as8(g0), ay0);
      ay1 = MF(Ay[it], as8(g1), ay1);
    }
    if (q == 0){
      eyf[(v * 2 + 0) * 32 + col]        = ay0[0];
      eyf[(v * 2 + 1) * 32 + col]        = ay0[1];
      eyf[(v * 2 + 0) * 32 + 16 + col]   = ay1[0];
      eyf[(v * 2 + 1) * 32 + 16 + col]   = ay1[1];
    }
    __syncthreads();
    if (isY && ys == s){
      float yv = byo;
      #pragma unroll
      for (int vv = 0; vv < 8; ++vv) yv += eyf[(vv * 2 + yp) * 32 + (yb & 31)];
      out[((size_t)yb * NT + 511) * MEL + w * 2 + yp] = yv;
    }
    __syncthreads();
  }
}

extern "C" void kernel_launch(void* const* d_in, const int* in_sizes, int n_in,
                              void* d_out, int out_size, void* d_ws, size_t ws_size,
                              hipStream_t stream){
  (void)in_sizes; (void)n_in; (void)out_size; (void)ws_size;
  const float* h0    = (const float*)d_in[1];
  const float* c0    = (const float*)d_in[2];
  const float* W_ih  = (const float*)d_in[3];
  const float* W_hh  = (const float*)d_in[4];
  const float* b_ih  = (const float*)d_in[5];
  const float* b_hh  = (const float*)d_in[6];
  const float* W_out = (const float*)d_in[7];
  const float* b_out = (const float*)d_in[8];
  float* out = (float*)d_out;

  char* p = (char*)d_ws;
  unsigned short* weff_b = (unsigned short*)p; p += (size_t)G4 * HDIM * 2;   // 33.5 MB
  unsigned short* wout_b = (unsigned short*)p; p += (size_t)MEL * HDIM * 2;  // 2 MB
  float* beff = (float*)p;  p += (size_t)G4 * 4;
  float* corr = (float*)p;  p += (size_t)G4 * NB * 4;                        // 2 MB
  float* ym1  = (float*)p;  p += (size_t)NB * MEL * 4;                       // 128 KB
  unsigned short* hbuf = (unsigned short*)p; p += (size_t)2 * NB * HDIM * 2; // 512 KB
  unsigned* slots0 = (unsigned*)p; p += NWG * sizeof(unsigned);
  unsigned* slots1 = (unsigned*)p; p += NWG * sizeof(unsigned);

  hipMemsetAsync(slots0, 0, 2 * NWG * sizeof(unsigned), stream);
  convert_kernel<<<256, 256, 0, stream>>>(W_out, wout_b, MEL * HDIM / 4);
  convert_kernel<<<64, 256, 0, stream>>>(h0, hbuf, NB * HDIM / 4);
  beff_kernel<<<G4, 64, 0, stream>>>(W_ih, b_ih, b_hh, b_out, beff);
  ym1_kernel<<<dim3(NB, MEL / 64), 64, 0, stream>>>(W_out, h0, b_out, ym1);
  corr_kernel<<<G4, NB, 0, stream>>>(W_ih, ym1, corr);
  weff_gemm<<<dim3(HDIM / 64, G4 / 64), 256, 0, stream>>>(W_ih, W_out, W_hh, weff_b);

  void* kargs[] = { (void*)&weff_b, (void*)&wout_b, (void*)&beff, (void*)&corr,
                    (void*)&c0, (void*)&b_out, (void*)&hbuf, (void*)&slots0, (void*)&slots1, (void*)&out };
  hipLaunchCooperativeKernel((const void*)decoder_coop, dim3(NWG), dim3(512), kargs, 0, stream);
}

// Round 8
// 4241.442 us; speedup vs baseline: 1.8064x; 1.3244x over previous
//
#include <hip/hip_runtime.h>

#define HDIM 2048   // LSTM_DIM
#define G4   8192   // 4*HDIM
#define NB   64     // BATCH
#define NT   512    // MAX_STEPS
#define MEL  512
#define KIN  512    // INPUT_SIZE
#define NWG  256    // 2 domains x 128

typedef __attribute__((ext_vector_type(8))) short short8;
typedef __attribute__((ext_vector_type(4))) float f32x4;
typedef __attribute__((ext_vector_type(4))) unsigned uint32x4;
typedef __attribute__((ext_vector_type(2))) unsigned uint32x2;

__device__ __forceinline__ unsigned short f2bf(float f){
  union { float f; unsigned u; } v; v.f = f;
  return (unsigned short)((v.u + 0x7fffu + ((v.u >> 16) & 1u)) >> 16);
}
__device__ __forceinline__ float sigm(float x){ return 1.f / (1.f + __expf(-x)); }
__device__ __forceinline__ float tanhfast(float x){ return 1.f - 2.f / (__expf(2.f * x) + 1.f); }

__device__ __forceinline__ f32x4 MF(short8 a, short8 b, f32x4 c){
  return __builtin_amdgcn_mfma_f32_16x16x32_bf16(a, b, c, 0, 0, 0);
}
__device__ __forceinline__ short8 as8(uint32x4 u){
  union { uint32x4 u; short8 s; } x; x.u = u; return x.s;
}
// IC bypass 16B load (no waitcnt inside; caller waits via counted vmcnt)
__device__ __forceinline__ void ld4b(uint32x4& d, const unsigned short* p){
  asm volatile("global_load_dwordx4 %0, %1, off sc0 sc1"
               : "=&v"(d) : "v"(p) : "memory");
}
// bypass 8B load with wait (slot poll: 128 slots / 64 lanes)
__device__ __forceinline__ uint32x2 ld_bypass2(const unsigned* p){
  uint32x2 r;
  asm volatile("global_load_dwordx2 %0, %1, off sc0 sc1\n\t"
               "s_waitcnt vmcnt(0)"
               : "=v"(r) : "v"(p) : "memory");
  return r;
}

// ---------------- fp32 -> bf16 convert ----------------
__global__ void convert_kernel(const float* __restrict__ src, unsigned short* __restrict__ dst, int n4){
  int stride = gridDim.x * blockDim.x;
  for (int i = blockIdx.x * blockDim.x + threadIdx.x; i < n4; i += stride){
    const float4 v = *(const float4*)(src + (size_t)i * 4);
    uint2 pk;
    pk.x = (unsigned)f2bf(v.x) | ((unsigned)f2bf(v.y) << 16);
    pk.y = (unsigned)f2bf(v.z) | ((unsigned)f2bf(v.w) << 16);
    *(uint2*)(dst + (size_t)i * 4) = pk;
  }
}

// ---------------- b_eff = b_ih + b_hh + W_ih @ b_out ----------------
__global__ void beff_kernel(const float* __restrict__ W_ih, const float* __restrict__ b_ih,
                            const float* __restrict__ b_hh, const float* __restrict__ b_out,
                            float* __restrict__ b_eff){
  int r = blockIdx.x;
  int lane = threadIdx.x;  // 64 threads = 1 wave
  float acc = 0.f;
  for (int k = lane; k < KIN; k += 64) acc += W_ih[(size_t)r * KIN + k] * b_out[k];
  #pragma unroll
  for (int off = 32; off > 0; off >>= 1) acc += __shfl_down(acc, off, 64);
  if (lane == 0) b_eff[r] = b_ih[r] + b_hh[r] + acc;
}

// ---------------- ym1[b][m] = Wout[m]·h0[b] + b_out[m] ----------------
__global__ void ym1_kernel(const float* __restrict__ Wout, const float* __restrict__ h0,
                           const float* __restrict__ b_out, float* __restrict__ ym1){
  const int b = blockIdx.x;
  const int m = blockIdx.y * 64 + threadIdx.x;
  const float* wr = Wout + (size_t)m * HDIM;
  const float* hr = h0 + (size_t)b * HDIM;
  float a0 = 0.f, a1 = 0.f, a2 = 0.f, a3 = 0.f;
  for (int k = 0; k < HDIM; k += 4){
    const float4 wv = *(const float4*)(wr + k);
    const float4 hv = *(const float4*)(hr + k);
    a0 += wv.x * hv.x; a1 += wv.y * hv.y; a2 += wv.z * hv.z; a3 += wv.w * hv.w;
  }
  ym1[(size_t)b * MEL + m] = a0 + a1 + a2 + a3 + b_out[m];
}

// ---------------- corr[r][b] = W_ih[r]·ym1[b] ----------------
__global__ void corr_kernel(const float* __restrict__ Wih, const float* __restrict__ ym1,
                            float* __restrict__ corr){
  const int r = blockIdx.x;
  const int b = threadIdx.x;
  const float* wr = Wih + (size_t)r * KIN;
  const float* yr = ym1 + (size_t)b * MEL;
  float a0 = 0.f, a1 = 0.f, a2 = 0.f, a3 = 0.f;
  for (int m = 0; m < KIN; m += 4){
    const float4 wv = *(const float4*)(wr + m);
    const float4 yv = *(const float4*)(yr + m);
    a0 += wv.x * yv.x; a1 += wv.y * yv.y; a2 += wv.z * yv.z; a3 += wv.w * yv.w;
  }
  corr[(size_t)r * NB + b] = a0 + a1 + a2 + a3;
}

// ---------------- W_eff = bf16( W_hh + W_ih @ W_out )  [8192 x 2048], K=512 ----------------
__global__ __launch_bounds__(256) void weff_gemm(const float* __restrict__ W_ih, const float* __restrict__ W_out,
                                                 const float* __restrict__ W_hh, unsigned short* __restrict__ Weff){
  __shared__ __align__(16) float As[32][68];  // [k][m]
  __shared__ __align__(16) float Bs[32][68];  // [k][n]
  const int bn = blockIdx.x * 64;
  const int bm = blockIdx.y * 64;
  const int t = threadIdx.x;
  const int tx = t & 15, ty = t >> 4;
  float acc[4][4] = {};
  for (int k0 = 0; k0 < KIN; k0 += 32){
    #pragma unroll
    for (int i = 0; i < 2; i++){
      int f = t + i * 256;
      int row = f >> 3, c4 = (f & 7) * 4;
      const float4 v = *(const float4*)(W_ih + (size_t)(bm + row) * KIN + k0 + c4);
      As[c4 + 0][row] = v.x; As[c4 + 1][row] = v.y; As[c4 + 2][row] = v.z; As[c4 + 3][row] = v.w;
    }
    #pragma unroll
    for (int i = 0; i < 2; i++){
      int f = t + i * 256;
      int kr = f >> 4, c4 = (f & 15) * 4;
      *(float4*)&Bs[kr][c4] = *(const float4*)(W_out + (size_t)(k0 + kr) * HDIM + bn + c4);
    }
    __syncthreads();
    #pragma unroll
    for (int kk = 0; kk < 32; kk++){
      const float4 av = *(const float4*)&As[kk][ty * 4];
      const float4 bv = *(const float4*)&Bs[kk][tx * 4];
      const float ar[4] = {av.x, av.y, av.z, av.w};
      const float br[4] = {bv.x, bv.y, bv.z, bv.w};
      #pragma unroll
      for (int i = 0; i < 4; i++)
        #pragma unroll
        for (int j = 0; j < 4; j++)
          acc[i][j] += ar[i] * br[j];
    }
    __syncthreads();
  }
  #pragma unroll
  for (int i = 0; i < 4; i++){
    const size_t row = (size_t)bm + ty * 4 + i;
    const float4 wh = *(const float4*)(W_hh + row * HDIM + bn + tx * 4);
    uint2 pk;
    pk.x = (unsigned)f2bf(acc[i][0] + wh.x) | ((unsigned)f2bf(acc[i][1] + wh.y) << 16);
    pk.y = (unsigned)f2bf(acc[i][2] + wh.z) | ((unsigned)f2bf(acc[i][3] + wh.w) << 16);
    *(uint2*)(Weff + row * HDIM + bn + tx * 4) = pk;
  }
}

// ---------------- per-wave wait: all 128 domain slots >= tgt (IC-coherent) ----------------
__device__ __forceinline__ void wait128(const unsigned* __restrict__ base, int lane, unsigned tgt){
  const unsigned* sp = base + lane * 2;
  while (true){
    uint32x2 vv = ld_bypass2(sp);
    unsigned m = vv.x < vv.y ? vv.x : vv.y;
    if (__all((int)(m >= tgt))) break;
    __builtin_amdgcn_s_sleep(1);
  }
}

// ---------------- persistent decoder: 2 batch-domains x 128 j-WGs ----------------
// Domain d owns batches [32d,32d+32) (2 sub-streams of 16). WG (d,jg) owns j-cols
// [16jg,16jg+16) -> 64 gate rows + 4 W_out rows; weights in VGPRs (wave v = k-slice
// [256v,256v+256), 160 VGPR/lane). Per stream-phase: 8 k-iters x 1 batch-tile.
// Gate exchange exf[8v][64lr][32 pitch] (R6-proven swizzle col^((lr&7)<<2), bijective
// in-row, 2-way banks both phases). eyf[8v][4][16]. Dynamic LDS = 67584 B.
// Sync: per (d,s) slot array of 128, fence-free IC protocol (R4/R6 proven).
#define LDSX (16384*4 + 512*4)

__global__ void __launch_bounds__(512, 1) decoder_coop(
    const unsigned short* __restrict__ Weff_b,
    const unsigned short* __restrict__ Wout_b,
    const float* __restrict__ b_eff,
    const float* __restrict__ corr,
    const float* __restrict__ c0,
    const float* __restrict__ b_out,
    unsigned short* __restrict__ hbuf,   // [2][64][2048] bf16; hbuf[0] = bf16(h0)
    unsigned* __restrict__ slots,        // [2][2][128] zeroed
    float* __restrict__ out)             // [64][512][512]
{
  extern __shared__ char smem[];
  float* exf = (float*)smem;             // 16384 floats
  float* eyf = exf + 16384;              // 512 floats
  const int bid  = blockIdx.x;
  const int d    = bid & 1;              // domain (interleaved across XCDs)
  const int jg   = bid >> 1;             // j-group 0..127
  const int tid  = threadIdx.x;
  const int v    = tid >> 6;             // wave = k-slice owner
  const int lane = tid & 63;
  const int col  = lane & 15;
  const int q    = lane >> 4;
  const int kbase = v * 256;

  // ---- A-fragment preload into VGPRs: 4 gate tiles + y tile ----
  short8 A0[8], A1[8], A2[8], A3[8], Ay[8];
  #pragma unroll
  for (int it = 0; it < 8; ++it){
    const size_t kc = (size_t)kbase + it * 32 + q * 8;
    A0[it] = *(const short8*)(Weff_b + (size_t)(0 * HDIM + jg * 16 + col) * HDIM + kc);
    A1[it] = *(const short8*)(Weff_b + (size_t)(1 * HDIM + jg * 16 + col) * HDIM + kc);
    A2[it] = *(const short8*)(Weff_b + (size_t)(2 * HDIM + jg * 16 + col) * HDIM + kc);
    A3[it] = *(const short8*)(Weff_b + (size_t)(3 * HDIM + jg * 16 + col) * HDIM + kc);
    if (col < 4)
      Ay[it] = *(const short8*)(Wout_b + (size_t)(jg * 4 + col) * HDIM + kc);
    else { short8 z = {0,0,0,0,0,0,0,0}; Ay[it] = z; }
  }

  // ---- reducer constants: tid<256 -> (jl, bs); per-stream c-state ----
  const int jl = tid & 15;
  const int bs = tid >> 4;               // 0..15 for tid<256
  const int rj = jg * 16 + jl;
  float be0 = 0.f, be1 = 0.f, be2 = 0.f, be3 = 0.f;
  float cs_s0 = 0.f, cs_s1 = 0.f;
  if (tid < 256){
    be0 = b_eff[0 * HDIM + rj]; be1 = b_eff[1 * HDIM + rj];
    be2 = b_eff[2 * HDIM + rj]; be3 = b_eff[3 * HDIM + rj];
    cs_s0 = c0[(size_t)(d * 32 + bs) * HDIM + rj];
    cs_s1 = c0[(size_t)(d * 32 + 16 + bs) * HDIM + rj];
  }
  const bool isY = (tid >= 256 && tid < 320);
  float byo = 0.f; int yr = 0, ybs = 0;
  if (isY){ const int yt = tid - 256; yr = yt & 3; ybs = yt >> 2; byo = b_out[jg * 4 + yr]; }

  // per-lane B element-offsets per stream
  int boff[2];
  #pragma unroll
  for (int s = 0; s < 2; ++s)
    boff[s] = (d * 32 + s * 16 + col) * HDIM + kbase + q * 8;

#define WAITV(N) asm volatile("s_waitcnt vmcnt(" #N ")" ::: "memory"); __builtin_amdgcn_sched_barrier(0);
#define MFM(IT, G) { \
    const short8 bv = as8(G); \
    a0 = MF(A0[IT], bv, a0); a1 = MF(A1[IT], bv, a1); \
    a2 = MF(A2[IT], bv, a2); a3 = MF(A3[IT], bv, a3); \
    ay = MF(Ay[IT], bv, ay); }

  for (int t = 0; t < NT; ++t){
    #pragma unroll
    for (int s = 0; s < 2; ++s){
      unsigned* slot_ds = slots + (d * 2 + s) * 128;
      if (t) wait128(slot_ds, lane, (unsigned)t);

      const unsigned short* hcur = hbuf + (size_t)(t & 1) * NB * HDIM;
      const int bo = boff[s];
      uint32x4 G0, G1, G2, G3;
      f32x4 a0 = {0,0,0,0}, a1 = {0,0,0,0}, a2 = {0,0,0,0}, a3 = {0,0,0,0}, ay = {0,0,0,0};

      ld4b(G0, hcur + bo);
      ld4b(G1, hcur + bo + 32);
      ld4b(G2, hcur + bo + 64);
      ld4b(G3, hcur + bo + 96);
      WAITV(3) MFM(0, G0) ld4b(G0, hcur + bo + 128);
      WAITV(3) MFM(1, G1) ld4b(G1, hcur + bo + 160);
      WAITV(3) MFM(2, G2) ld4b(G2, hcur + bo + 192);
      WAITV(3) MFM(3, G3) ld4b(G3, hcur + bo + 224);
      WAITV(3) MFM(4, G0)
      WAITV(2) MFM(5, G1)
      WAITV(1) MFM(6, G2)
      WAITV(0) MFM(7, G3)

      // ---- exchange stores: pitch 32, swizzle col^((lr&7)<<2) (bijective in-row) ----
      #pragma unroll
      for (int e = 0; e < 4; ++e){
        const int lr = q * 4 + e;
        const int cx = col ^ ((lr & 7) << 2);
        exf[(v * 64 +  0 + lr) * 32 + cx] = a0[e];
        exf[(v * 64 + 16 + lr) * 32 + cx] = a1[e];
        exf[(v * 64 + 32 + lr) * 32 + cx] = a2[e];
        exf[(v * 64 + 48 + lr) * 32 + cx] = a3[e];
      }
      if (q == 0){
        #pragma unroll
        for (int e = 0; e < 4; ++e) eyf[(v * 4 + e) * 16 + col] = ay[e];
      }
      __syncthreads();

      if (tid < 256){
        const int cidx = bs ^ ((jl & 7) << 2);
        float gi = 0.f, gf = 0.f, gg = 0.f, go = 0.f;
        #pragma unroll
        for (int vv = 0; vv < 8; ++vv){
          gi += exf[(vv * 64 +  0 + jl) * 32 + cidx];
          gf += exf[(vv * 64 + 16 + jl) * 32 + cidx];
          gg += exf[(vv * 64 + 32 + jl) * 32 + cidx];
          go += exf[(vv * 64 + 48 + jl) * 32 + cidx];
        }
        const int b = d * 32 + s * 16 + bs;
        gi += be0; gf += be1; gg += be2; go += be3;
        if (t == 0){
          gi -= corr[(size_t)(0 * HDIM + rj) * NB + b];
          gf -= corr[(size_t)(1 * HDIM + rj) * NB + b];
          gg -= corr[(size_t)(2 * HDIM + rj) * NB + b];
          go -= corr[(size_t)(3 * HDIM + rj) * NB + b];
        }
        float cs = s ? cs_s1 : cs_s0;
        const float i_ = sigm(gi), f_ = sigm(gf), g_ = tanhfast(gg), o_ = sigm(go);
        cs = f_ * cs + i_ * g_;
        const float hn = o_ * tanhfast(cs);
        if (s) cs_s1 = cs; else cs_s0 = cs;

        // pack adjacent jl via shfl, 4B agent-scope store to IC
        const float pn = __shfl_xor(hn, 1, 64);
        unsigned short* hdst = hbuf + (size_t)((t + 1) & 1) * NB * HDIM;
        if ((jl & 1) == 0){
          const unsigned pk = (unsigned)f2bf(hn) | ((unsigned)f2bf(pn) << 16);
          __hip_atomic_store((unsigned*)(hdst + (size_t)b * HDIM + rj), pk,
                             __ATOMIC_RELAXED, __HIP_MEMORY_SCOPE_AGENT);
        }
      } else if (isY && t >= 1){
        float yv = byo;
        #pragma unroll
        for (int vv = 0; vv < 8; ++vv) yv += eyf[(vv * 4 + yr) * 16 + ybs];
        const int b = d * 32 + s * 16 + ybs;
        out[((size_t)b * NT + (t - 1)) * MEL + jg * 4 + yr] = yv;
      }
      __syncthreads();   // drains vmcnt (h at IC) + protects exf reuse
      if (tid == 0)
        __hip_atomic_store(slot_ds + jg, (unsigned)(t + 1),
                           __ATOMIC_RELAXED, __HIP_MEMORY_SCOPE_AGENT);
    }
  }

  // ---- final frame: y_511 = h_512 @ Wout^T + b_out (h_512 in hbuf[0], NT even) ----
  #pragma unroll
  for (int s = 0; s < 2; ++s){
    wait128(slots + (d * 2 + s) * 128, lane, (unsigned)NT);
    const int bo = boff[s];
    f32x4 ay = {0,0,0,0};
    #pragma unroll
    for (int it = 0; it < 8; ++it){
      uint32x4 g;
      ld4b(g, hbuf + bo + it * 32);
      asm volatile("s_waitcnt vmcnt(0)" ::: "memory");
      __builtin_amdgcn_sched_barrier(0);
      ay = MF(Ay[it], as8(g), ay);
    }
    if (q == 0){
      #pragma unroll
      for (int e = 0; e < 4; ++e) eyf[(v * 4 + e) * 16 + col] = ay[e];
    }
    __syncthreads();
    if (isY){
      float yv = byo;
      #pragma unroll
      for (int vv = 0; vv < 8; ++vv) yv += eyf[(vv * 4 + yr) * 16 + ybs];
      const int b = d * 32 + s * 16 + ybs;
      out[((size_t)b * NT + 511) * MEL + jg * 4 + yr] = yv;
    }
    __syncthreads();
  }
}

extern "C" void kernel_launch(void* const* d_in, const int* in_sizes, int n_in,
                              void* d_out, int out_size, void* d_ws, size_t ws_size,
                              hipStream_t stream){
  (void)in_sizes; (void)n_in; (void)out_size; (void)ws_size;
  const float* h0    = (const float*)d_in[1];
  const float* c0    = (const float*)d_in[2];
  const float* W_ih  = (const float*)d_in[3];
  const float* W_hh  = (const float*)d_in[4];
  const float* b_ih  = (const float*)d_in[5];
  const float* b_hh  = (const float*)d_in[6];
  const float* W_out = (const float*)d_in[7];
  const float* b_out = (const float*)d_in[8];
  float* out = (float*)d_out;

  char* p = (char*)d_ws;
  unsigned short* weff_b = (unsigned short*)p; p += (size_t)G4 * HDIM * 2;   // 33.5 MB
  unsigned short* wout_b = (unsigned short*)p; p += (size_t)MEL * HDIM * 2;  // 2 MB
  float* beff = (float*)p;  p += (size_t)G4 * 4;
  float* corr = (float*)p;  p += (size_t)G4 * NB * 4;                        // 2 MB
  float* ym1  = (float*)p;  p += (size_t)NB * MEL * 4;                       // 128 KB
  unsigned short* hbuf = (unsigned short*)p; p += (size_t)2 * NB * HDIM * 2; // 512 KB
  unsigned* slots = (unsigned*)p; p += 4 * 128 * sizeof(unsigned);

  hipMemsetAsync(slots, 0, 4 * 128 * sizeof(unsigned), stream);
  convert_kernel<<<256, 256, 0, stream>>>(W_out, wout_b, MEL * HDIM / 4);
  convert_kernel<<<64, 256, 0, stream>>>(h0, hbuf, NB * HDIM / 4);
  beff_kernel<<<G4, 64, 0, stream>>>(W_ih, b_ih, b_hh, b_out, beff);
  ym1_kernel<<<dim3(NB, MEL / 64), 64, 0, stream>>>(W_out, h0, b_out, ym1);
  corr_kernel<<<G4, NB, 0, stream>>>(W_ih, ym1, corr);
  weff_gemm<<<dim3(HDIM / 64, G4 / 64), 256, 0, stream>>>(W_ih, W_out, W_hh, weff_b);

  hipFuncSetAttribute((const void*)decoder_coop, hipFuncAttributeMaxDynamicSharedMemorySize, LDSX);
  void* kargs[] = { (void*)&weff_b, (void*)&wout_b, (void*)&beff, (void*)&corr,
                    (void*)&c0, (void*)&b_out, (void*)&hbuf, (void*)&slots, (void*)&out };
  hipLaunchCooperativeKernel((const void*)decoder_coop, dim3(NWG), dim3(512), kargs, LDSX, stream);
}